// Round 6
// baseline (1003.500 us; speedup 1.0000x reference)
//
#include <hip/hip_runtime.h>
#include <hip/hip_fp16.h>

#define N_NODES 100000
#define N_EDGESV 1000000
#define N_REL 7
#define IN_CH 128
#define HID_CH 64
#define OUT_CH 2
#define NB 4
#define DI 32
#define DO 16
#define SCAN_CHUNK 1024
#define NCHUNKS ((N_NODES + SCAN_CHUNK - 1) / SCAN_CHUNK)  // 98
#define NEGI -3.0e38f
#define NEGTEST -1.0e38f
#define OFFMASK 0x0FFFFFFF

// ================= CSR build =================
__global__ void hist_kernel(const int* __restrict__ ei, int* __restrict__ deg) {
    int e = blockIdx.x * blockDim.x + threadIdx.x;
    if (e < N_EDGESV) atomicAdd(&deg[ei[N_EDGESV + e]], 1);
}

__global__ void scan1_kernel(const int* __restrict__ deg, int* __restrict__ off,
                             int* __restrict__ sums) {
    __shared__ int lds[256];
    const int tid = threadIdx.x;
    const int base = blockIdx.x * SCAN_CHUNK + tid * 4;
    int v0 = (base + 0 < N_NODES) ? deg[base + 0] : 0;
    int v1 = (base + 1 < N_NODES) ? deg[base + 1] : 0;
    int v2 = (base + 2 < N_NODES) ? deg[base + 2] : 0;
    int v3 = (base + 3 < N_NODES) ? deg[base + 3] : 0;
    int t0 = v0, t1 = v0 + v1, t2 = t1 + v2, t3 = t2 + v3;
    lds[tid] = t3;
    __syncthreads();
    for (int d = 1; d < 256; d <<= 1) {
        int t = (tid >= d) ? lds[tid - d] : 0;
        __syncthreads();
        if (tid >= d) lds[tid] += t;
        __syncthreads();
    }
    int excl = lds[tid] - t3;
    if (base + 0 < N_NODES) off[base + 1] = excl + t0;
    if (base + 1 < N_NODES) off[base + 2] = excl + t1;
    if (base + 2 < N_NODES) off[base + 3] = excl + t2;
    if (base + 3 < N_NODES) off[base + 4] = excl + t3;
    if (tid == 255) sums[blockIdx.x] = lds[255];
}

__global__ void scan2_kernel(int* __restrict__ sums) {
    __shared__ int lds[128];
    int t = threadIdx.x;
    lds[t] = (t < NCHUNKS) ? sums[t] : 0;
    __syncthreads();
    for (int d = 1; d < 128; d <<= 1) {
        int v = (t >= d) ? lds[t - d] : 0;
        __syncthreads();
        if (t >= d) lds[t] += v;
        __syncthreads();
    }
    if (t < NCHUNKS) sums[t] = lds[t];
}

__global__ void scan3_kernel(int* __restrict__ off, const int* __restrict__ sums,
                             int* __restrict__ cursor) {
    int i = blockIdx.x * blockDim.x + threadIdx.x;
    if (i == 0) { off[0] = 0; cursor[0] = 0; }
    if (i < N_NODES) {
        int chunk = i / SCAN_CHUNK;
        int v = off[i + 1] + ((chunk > 0) ? sums[chunk - 1] : 0);
        off[i + 1] = v;
        cursor[i + 1] = v;
    }
}

// packed1: byte offset into msg1 (src*896 + r*128) | r<<28
// packed2: byte offset into msg2 (src*64 + r*8); r = (pk>>3)&7
__global__ void scatter_kernel(const int* __restrict__ ei, const int* __restrict__ et,
                               int* __restrict__ cursor, int* __restrict__ packed1,
                               int* __restrict__ packed2) {
    int e = blockIdx.x * blockDim.x + threadIdx.x;
    if (e < N_EDGESV) {
        int d = ei[N_EDGESV + e];
        int s = ei[e];
        int r = et[e];
        int pos = atomicAdd(&cursor[d], 1);
        packed1[pos] = (s * 896 + r * 128) | (r << 28);
        packed2[pos] = s * 64 + r * 8;
    }
}

// ========== rootmm: hroot = x@root1 + bias1; W in 128 VGPRs, 2 nodes/iter ==========
__global__ __launch_bounds__(256)
void rootmm_kernel(const float* __restrict__ x, const float* __restrict__ root1,
                   const float* __restrict__ bias1, float* __restrict__ hroot)
{
    const int lane = threadIdx.x & 63;  // output channel
    float w[IN_CH];
#pragma unroll
    for (int i = 0; i < IN_CH; ++i) w[i] = root1[i * HID_CH + lane];  // coalesced, once
    const float bias = bias1[lane];

    const int wid = blockIdx.x * (blockDim.x >> 6) + (threadIdx.x >> 6);
    const int nw = gridDim.x * (blockDim.x >> 6);
    const int NPAIR = N_NODES / 2;

    for (int np = wid; np < NPAIR; np += nw) {
        const int n0 = np * 2;  // adjacent rows -> contiguous 1KB window in x
        const float4* xr0 = (const float4*)(x + ((size_t)n0 << 7));
        const float4* xr1 = xr0 + 32;
        float acc0 = bias, acc1 = bias;
#pragma unroll
        for (int i4 = 0; i4 < 32; ++i4) {
            float4 a = xr0[i4];  // independent broadcast loads, 2 chains in flight
            float4 c = xr1[i4];
            acc0 = fmaf(a.x, w[i4 * 4 + 0], acc0);
            acc0 = fmaf(a.y, w[i4 * 4 + 1], acc0);
            acc0 = fmaf(a.z, w[i4 * 4 + 2], acc0);
            acc0 = fmaf(a.w, w[i4 * 4 + 3], acc0);
            acc1 = fmaf(c.x, w[i4 * 4 + 0], acc1);
            acc1 = fmaf(c.y, w[i4 * 4 + 1], acc1);
            acc1 = fmaf(c.z, w[i4 * 4 + 2], acc1);
            acc1 = fmaf(c.w, w[i4 * 4 + 3], acc1);
        }
        hroot[((size_t)n0 << 6) + lane] = acc0;
        hroot[((size_t)(n0 + 1) << 6) + lane] = acc1;
    }
}

// ========== pre1: msg1[n][r][c] fp16; 4 or 3 relations per block, W in VGPRs ==========
__global__ __launch_bounds__(256)
void pre1_kernel(const float* __restrict__ x, const float* __restrict__ W1,
                 __half* __restrict__ msg1)
{
    const int grp = blockIdx.x & 1;          // 0: r=0..3  1: r=4..6
    const int rbase = grp ? 4 : 0;
    const int nr = grp ? 3 : 4;
    const int lane = threadIdx.x & 63;
    const int b = lane >> 4;
    const int j = lane & 15;

    float w[4][DI];  // up to 128 weight VGPRs, loaded once
    for (int rr = 0; rr < nr; ++rr) {
        const float* wp = W1 + ((size_t)((rbase + rr) * NB + b) * DI) * DO + j;
#pragma unroll
        for (int i = 0; i < DI; ++i) w[rr][i] = wp[i * DO];
    }

    const int wid = (blockIdx.x >> 1) * (blockDim.x >> 6) + (threadIdx.x >> 6);
    const int nw = (gridDim.x >> 1) * (blockDim.x >> 6);
    const int NPAIR = N_NODES / 2;

    for (int np = wid; np < NPAIR; np += nw) {
        const int n0 = np * 2;
        const float4* xr0 = (const float4*)(x + ((size_t)n0 << 7)) + (b << 3);
        const float4* xr1 = xr0 + 32;
        float4 xa[8], xb[8];
#pragma unroll
        for (int i4 = 0; i4 < 8; ++i4) { xa[i4] = xr0[i4]; xb[i4] = xr1[i4]; }
        __half* m0 = msg1 + (size_t)n0 * (N_REL * HID_CH) + (rbase << 6) + lane;
        __half* m1 = m0 + (N_REL * HID_CH);
        for (int rr = 0; rr < nr; ++rr) {
            float s0 = 0.f, s1 = 0.f;
#pragma unroll
            for (int i4 = 0; i4 < 8; ++i4) {
                s0 = fmaf(xa[i4].x, w[rr][i4 * 4 + 0], s0);
                s0 = fmaf(xa[i4].y, w[rr][i4 * 4 + 1], s0);
                s0 = fmaf(xa[i4].z, w[rr][i4 * 4 + 2], s0);
                s0 = fmaf(xa[i4].w, w[rr][i4 * 4 + 3], s0);
                s1 = fmaf(xb[i4].x, w[rr][i4 * 4 + 0], s1);
                s1 = fmaf(xb[i4].y, w[rr][i4 * 4 + 1], s1);
                s1 = fmaf(xb[i4].z, w[rr][i4 * 4 + 2], s1);
                s1 = fmaf(xb[i4].w, w[rr][i4 * 4 + 3], s1);
            }
            m0[rr << 6] = __float2half(s0);  // 128B coalesced per (n,r)
            m1[rr << 6] = __float2half(s1);
        }
    }
}

// ========== agg1: wave/node; gather fp16 msgs via byte offsets; fuse relu+msg2 ==========
__global__ __launch_bounds__(256, 6)
void agg1_kernel(const __half* __restrict__ msg1, const float* __restrict__ hroot,
                 const int* __restrict__ off, const int* __restrict__ packed1,
                 const float* __restrict__ comp2, const float* __restrict__ basis2,
                 const float* __restrict__ root2, const float* __restrict__ bias2,
                 float* __restrict__ msg2)
{
    __shared__ float w2[N_REL * 2 * HID_CH];  // [r][o][i], 3.5 KB
    for (int idx = threadIdx.x; idx < N_REL * 2 * HID_CH; idx += blockDim.x) {
        int i = idx & 63;
        int o = (idx >> 6) & 1;
        int r = idx >> 7;
        float v = 0.f;
#pragma unroll
        for (int bb = 0; bb < NB; ++bb)
            v += comp2[r * NB + bb] * basis2[(bb * HID_CH + i) * OUT_CH + o];
        w2[idx] = v;
    }
    __syncthreads();

    const int lane = threadIdx.x & 63;
    const int n = blockIdx.x * (blockDim.x >> 6) + (threadIdx.x >> 6);
    if (n >= N_NODES) return;

    const char* m1 = (const char*)msg1;
    const int lane2 = lane * 2;
    const int st = off[n], en = off[n + 1];
    float a0 = NEGI, a1 = NEGI, a2 = NEGI, a3 = NEGI, a4 = NEGI, a5 = NEGI, a6 = NEGI;

#define SEL(r_, v_) \
    a0 = fmaxf(a0, (r_ == 0) ? v_ : NEGI); \
    a1 = fmaxf(a1, (r_ == 1) ? v_ : NEGI); \
    a2 = fmaxf(a2, (r_ == 2) ? v_ : NEGI); \
    a3 = fmaxf(a3, (r_ == 3) ? v_ : NEGI); \
    a4 = fmaxf(a4, (r_ == 4) ? v_ : NEGI); \
    a5 = fmaxf(a5, (r_ == 5) ? v_ : NEGI); \
    a6 = fmaxf(a6, (r_ == 6) ? v_ : NEGI);

    int p = st;
    for (; p + 3 < en; p += 4) {  // 4 gathers in flight
        unsigned k0 = (unsigned)packed1[p];
        unsigned k1 = (unsigned)packed1[p + 1];
        unsigned k2 = (unsigned)packed1[p + 2];
        unsigned k3 = (unsigned)packed1[p + 3];
        float v0 = __half2float(*(const __half*)(m1 + ((k0 & OFFMASK) + lane2)));
        float v1 = __half2float(*(const __half*)(m1 + ((k1 & OFFMASK) + lane2)));
        float v2 = __half2float(*(const __half*)(m1 + ((k2 & OFFMASK) + lane2)));
        float v3 = __half2float(*(const __half*)(m1 + ((k3 & OFFMASK) + lane2)));
        int r0 = k0 >> 28, r1 = k1 >> 28, r2 = k2 >> 28, r3 = k3 >> 28;
        SEL(r0, v0) SEL(r1, v1) SEL(r2, v2) SEL(r3, v3)
    }
    for (; p < en; ++p) {
        unsigned k0 = (unsigned)packed1[p];
        float v0 = __half2float(*(const __half*)(m1 + ((k0 & OFFMASK) + lane2)));
        int r0 = k0 >> 28;
        SEL(r0, v0)
    }
#undef SEL

    float add = 0.f;
    add += (a0 > NEGTEST) ? a0 : 0.f;
    add += (a1 > NEGTEST) ? a1 : 0.f;
    add += (a2 > NEGTEST) ? a2 : 0.f;
    add += (a3 > NEGTEST) ? a3 : 0.f;
    add += (a4 > NEGTEST) ? a4 : 0.f;
    add += (a5 > NEGTEST) ? a5 : 0.f;
    add += (a6 > NEGTEST) ? a6 : 0.f;

    const float h = fmaxf(hroot[((size_t)n << 6) + lane] + add, 0.f);

    // ---- layer-2 message precompute: 14 dot-products + self term ----
    float o[16];
#pragma unroll
    for (int r = 0; r < N_REL; ++r) {
        float t0 = h * w2[r * 128 + lane];
        float t1 = h * w2[r * 128 + 64 + lane];
#pragma unroll
        for (int s = 32; s > 0; s >>= 1) {
            t0 += __shfl_xor(t0, s);
            t1 += __shfl_xor(t1, s);
        }
        o[r * 2] = t0;
        o[r * 2 + 1] = t1;
    }
    {
        float u0 = h * root2[lane * 2 + 0];
        float u1 = h * root2[lane * 2 + 1];
#pragma unroll
        for (int s = 32; s > 0; s >>= 1) {
            u0 += __shfl_xor(u0, s);
            u1 += __shfl_xor(u1, s);
        }
        o[14] = u0 + bias2[0];
        o[15] = u1 + bias2[1];
    }
    if (lane == 0) {
        float4* dst = (float4*)(msg2 + (size_t)n * 16);
        dst[0] = make_float4(o[0], o[1], o[2], o[3]);
        dst[1] = make_float4(o[4], o[5], o[6], o[7]);
        dst[2] = make_float4(o[8], o[9], o[10], o[11]);
        dst[3] = make_float4(o[12], o[13], o[14], o[15]);
    }
}

// ========== agg2: thread/node; float2 gathers via byte offsets ==========
__global__ __launch_bounds__(256)
void agg2_kernel(const float* __restrict__ msg2, const int* __restrict__ off,
                 const int* __restrict__ packed2, float* __restrict__ out)
{
    const int n = blockIdx.x * blockDim.x + threadIdx.x;
    if (n >= N_NODES) return;
    const char* m2 = (const char*)msg2;
    const int st = off[n], en = off[n + 1];
    float o0 = msg2[(size_t)n * 16 + 14];  // self + bias pre-folded
    float o1 = msg2[(size_t)n * 16 + 15];
    float ax[7], ay[7];
#pragma unroll
    for (int k = 0; k < 7; ++k) { ax[k] = NEGI; ay[k] = NEGI; }
    for (int p = st; p < en; ++p) {
        int pk = packed2[p];
        int r = (pk >> 3) & 7;
        const float2 f = *(const float2*)(m2 + pk);
#pragma unroll
        for (int k = 0; k < 7; ++k) {
            ax[k] = fmaxf(ax[k], (r == k) ? f.x : NEGI);
            ay[k] = fmaxf(ay[k], (r == k) ? f.y : NEGI);
        }
    }
#pragma unroll
    for (int k = 0; k < 7; ++k) {
        o0 += (ax[k] > NEGTEST) ? ax[k] : 0.f;
        o1 += (ay[k] > NEGTEST) ? ay[k] : 0.f;
    }
    out[(size_t)n * OUT_CH + 0] = o0;
    out[(size_t)n * OUT_CH + 1] = o1;
}

extern "C" void kernel_launch(void* const* d_in, const int* in_sizes, int n_in,
                              void* d_out, int out_size, void* d_ws, size_t ws_size,
                              hipStream_t stream)
{
    const float* x      = (const float*)d_in[0];
    const int*   ei     = (const int*)d_in[1];
    const int*   et     = (const int*)d_in[2];
    const float* W1     = (const float*)d_in[3];
    const float* root1  = (const float*)d_in[4];
    const float* bias1  = (const float*)d_in[5];
    const float* comp2  = (const float*)d_in[6];
    const float* basis2 = (const float*)d_in[7];
    const float* root2  = (const float*)d_in[8];
    const float* bias2  = (const float*)d_in[9];
    float* out = (float*)d_out;

    // workspace carve-up (~135 MB)
    char* ws = (char*)d_ws;
    size_t o = 0;
    auto carve = [&](size_t bytes) { char* p = ws + o; o += (bytes + 255) & ~(size_t)255; return p; };
    int*    deg     = (int*)carve(sizeof(int) * N_NODES);
    int*    off     = (int*)carve(sizeof(int) * (N_NODES + 1));
    int*    cursor  = (int*)carve(sizeof(int) * (N_NODES + 1));
    int*    sums    = (int*)carve(sizeof(int) * 128);
    int*    packed1 = (int*)carve(sizeof(int) * N_EDGESV);
    int*    packed2 = (int*)carve(sizeof(int) * N_EDGESV);
    __half* msg1    = (__half*)carve(sizeof(__half) * (size_t)N_NODES * N_REL * HID_CH); // 89.6 MB
    float*  hroot   = (float*)carve(sizeof(float) * (size_t)N_NODES * HID_CH);           // 25.6 MB
    float*  msg2    = (float*)carve(sizeof(float) * (size_t)N_NODES * 16);               //  6.4 MB

    // ---- CSR build ----
    hipMemsetAsync(deg, 0, sizeof(int) * N_NODES, stream);
    hist_kernel<<<(N_EDGESV + 255) / 256, 256, 0, stream>>>(ei, deg);
    scan1_kernel<<<NCHUNKS, 256, 0, stream>>>(deg, off, sums);
    scan2_kernel<<<1, 128, 0, stream>>>(sums);
    scan3_kernel<<<(N_NODES + 255) / 256, 256, 0, stream>>>(off, sums, cursor);
    scatter_kernel<<<(N_EDGESV + 255) / 256, 256, 0, stream>>>(ei, et, cursor, packed1, packed2);

    // ---- dense precomputes (weights in registers, 2-node ILP) ----
    rootmm_kernel<<<1024, 256, 0, stream>>>(x, root1, bias1, hroot);
    pre1_kernel<<<2048, 256, 0, stream>>>(x, W1, msg1);

    // ---- layer 1 aggregation (+ fused layer-2 message build) ----
    agg1_kernel<<<(N_NODES + 3) / 4, 256, 0, stream>>>(msg1, hroot, off, packed1,
                                                       comp2, basis2, root2, bias2, msg2);

    // ---- layer 2 aggregation ----
    agg2_kernel<<<(N_NODES + 255) / 256, 256, 0, stream>>>(msg2, off, packed2, out);
}

// Round 7
// 601.067 us; speedup vs baseline: 1.6695x; 1.6695x over previous
//
#include <hip/hip_runtime.h>
#include <hip/hip_fp16.h>

#define N_NODES 100000
#define N_EDGESV 1000000
#define N_REL 7
#define IN_CH 128
#define HID_CH 64
#define OUT_CH 2
#define NB 4
#define DI 32
#define DO 16
#define NBINS 800000          // (dst, rel) bins: key = d*8 + r
#define SCAN_CHUNK 1024
#define NCHUNK2 ((NBINS + SCAN_CHUNK - 1) / SCAN_CHUNK)  // 782
#define NEGI -3.0e38f

// ================= CSR build over (dst, rel) keys =================
__global__ void hist_kernel(const int* __restrict__ ei, const int* __restrict__ et,
                            int* __restrict__ deg2) {
    int e = blockIdx.x * blockDim.x + threadIdx.x;
    if (e < N_EDGESV) atomicAdd(&deg2[(ei[N_EDGESV + e] << 3) + et[e]], 1);
}

__global__ void scan1_kernel(const int* __restrict__ deg2, int* __restrict__ off2,
                             int* __restrict__ sums) {
    __shared__ int lds[256];
    const int tid = threadIdx.x;
    const int base = blockIdx.x * SCAN_CHUNK + tid * 4;
    int v0 = (base + 0 < NBINS) ? deg2[base + 0] : 0;
    int v1 = (base + 1 < NBINS) ? deg2[base + 1] : 0;
    int v2 = (base + 2 < NBINS) ? deg2[base + 2] : 0;
    int v3 = (base + 3 < NBINS) ? deg2[base + 3] : 0;
    int t0 = v0, t1 = v0 + v1, t2 = t1 + v2, t3 = t2 + v3;
    lds[tid] = t3;
    __syncthreads();
    for (int d = 1; d < 256; d <<= 1) {
        int t = (tid >= d) ? lds[tid - d] : 0;
        __syncthreads();
        if (tid >= d) lds[tid] += t;
        __syncthreads();
    }
    int excl = lds[tid] - t3;
    if (base + 0 < NBINS) off2[base + 1] = excl + t0;
    if (base + 1 < NBINS) off2[base + 2] = excl + t1;
    if (base + 2 < NBINS) off2[base + 3] = excl + t2;
    if (base + 3 < NBINS) off2[base + 4] = excl + t3;
    if (tid == 255) sums[blockIdx.x] = lds[255];
}

__global__ void scan2_kernel(int* __restrict__ sums) {
    __shared__ int lds[1024];
    int t = threadIdx.x;
    lds[t] = (t < NCHUNK2) ? sums[t] : 0;
    __syncthreads();
    for (int d = 1; d < 1024; d <<= 1) {
        int v = (t >= d) ? lds[t - d] : 0;
        __syncthreads();
        if (t >= d) lds[t] += v;
        __syncthreads();
    }
    if (t < NCHUNK2) sums[t] = lds[t];
}

__global__ void scan3_kernel(int* __restrict__ off2, const int* __restrict__ sums,
                             int* __restrict__ cursor2) {
    int i = blockIdx.x * blockDim.x + threadIdx.x;
    if (i == 0) { off2[0] = 0; cursor2[0] = 0; }
    if (i < NBINS) {
        int chunk = i / SCAN_CHUNK;
        int v = off2[i + 1] + ((chunk > 0) ? sums[chunk - 1] : 0);
        off2[i + 1] = v;
        cursor2[i + 1] = v;
    }
}

// packed1: byte offset into msg1 = s*896 + r*128 (r implied by segment)
// packed2: byte offset into msg2 = s*64 + r*8
__global__ void scatter_kernel(const int* __restrict__ ei, const int* __restrict__ et,
                               int* __restrict__ cursor2, int* __restrict__ packed1,
                               int* __restrict__ packed2) {
    int e = blockIdx.x * blockDim.x + threadIdx.x;
    if (e < N_EDGESV) {
        int d = ei[N_EDGESV + e];
        int s = ei[e];
        int r = et[e];
        int pos = atomicAdd(&cursor2[(d << 3) + r], 1);
        packed1[pos] = s * 896 + r * 128;
        packed2[pos] = s * 64 + r * 8;
    }
}

// ========== rootmm: K-split halves. hrootp[q][n][c] = x[n][64q:64q+64]@root1_half ==========
__global__ __launch_bounds__(256)
void rootmm_kernel(const float* __restrict__ x, const float* __restrict__ root1,
                   float* __restrict__ hrootp)
{
    const int lane = threadIdx.x & 63;  // output channel
    const int wid = blockIdx.x * 4 + (threadIdx.x >> 6);
    const int nw = gridDim.x * 4;
    const int q = wid & 1;              // K half (fixed per wave)

    float w[64];
#pragma unroll
    for (int i = 0; i < 64; ++i) w[i] = root1[(q * 64 + i) * HID_CH + lane];

    float* hp = hrootp + (size_t)q * N_NODES * HID_CH;
    const int NPAIR = N_NODES / 2;
    for (int np = (wid >> 1); np < NPAIR; np += (nw >> 1)) {
        const int n0 = np * 2;
        const float4* xr0 = (const float4*)(x + (size_t)n0 * IN_CH + q * 64);
        const float4* xr1 = (const float4*)(x + (size_t)(n0 + 1) * IN_CH + q * 64);
        float acc0 = 0.f, acc1 = 0.f;
#pragma unroll
        for (int i4 = 0; i4 < 16; ++i4) {
            float4 a = xr0[i4];
            float4 c = xr1[i4];
            acc0 = fmaf(a.x, w[i4 * 4 + 0], acc0);
            acc0 = fmaf(a.y, w[i4 * 4 + 1], acc0);
            acc0 = fmaf(a.z, w[i4 * 4 + 2], acc0);
            acc0 = fmaf(a.w, w[i4 * 4 + 3], acc0);
            acc1 = fmaf(c.x, w[i4 * 4 + 0], acc1);
            acc1 = fmaf(c.y, w[i4 * 4 + 1], acc1);
            acc1 = fmaf(c.z, w[i4 * 4 + 2], acc1);
            acc1 = fmaf(c.w, w[i4 * 4 + 3], acc1);
        }
        hp[(size_t)n0 * HID_CH + lane] = acc0;
        hp[(size_t)(n0 + 1) * HID_CH + lane] = acc1;
    }
}

// ========== pre1: msg1[n][r][c] fp16; COMPILE-TIME NR (no scratch spill!) ==========
template<int RBASE, int NR>
__device__ __forceinline__ void pre1_work(const float* __restrict__ x,
                                          const float* __restrict__ W1,
                                          __half* __restrict__ msg1,
                                          int wid, int nw)
{
    const int lane = threadIdx.x & 63;
    const int b = lane >> 4;
    const int j = lane & 15;

    float w[NR][DI];  // static indices after full unroll -> real VGPRs
#pragma unroll
    for (int rr = 0; rr < NR; ++rr) {
        const float* wp = W1 + ((size_t)((RBASE + rr) * NB + b) * DI) * DO + j;
#pragma unroll
        for (int i = 0; i < DI; ++i) w[rr][i] = wp[i * DO];
    }

    const int NPAIR = N_NODES / 2;
    for (int np = wid; np < NPAIR; np += nw) {
        const int n0 = np * 2;
        const float4* xr0 = (const float4*)(x + ((size_t)n0 << 7)) + (b << 3);
        const float4* xr1 = xr0 + 32;
        float4 xa[8], xb[8];
#pragma unroll
        for (int i4 = 0; i4 < 8; ++i4) { xa[i4] = xr0[i4]; xb[i4] = xr1[i4]; }
        __half* m0 = msg1 + (size_t)n0 * (N_REL * HID_CH) + (RBASE << 6) + lane;
        __half* m1 = m0 + N_REL * HID_CH;
#pragma unroll
        for (int rr = 0; rr < NR; ++rr) {
            float s0 = 0.f, s1 = 0.f;
#pragma unroll
            for (int i4 = 0; i4 < 8; ++i4) {
                s0 = fmaf(xa[i4].x, w[rr][i4 * 4 + 0], s0);
                s0 = fmaf(xa[i4].y, w[rr][i4 * 4 + 1], s0);
                s0 = fmaf(xa[i4].z, w[rr][i4 * 4 + 2], s0);
                s0 = fmaf(xa[i4].w, w[rr][i4 * 4 + 3], s0);
                s1 = fmaf(xb[i4].x, w[rr][i4 * 4 + 0], s1);
                s1 = fmaf(xb[i4].y, w[rr][i4 * 4 + 1], s1);
                s1 = fmaf(xb[i4].z, w[rr][i4 * 4 + 2], s1);
                s1 = fmaf(xb[i4].w, w[rr][i4 * 4 + 3], s1);
            }
            m0[rr << 6] = __float2half(s0);
            m1[rr << 6] = __float2half(s1);
        }
    }
}

__global__ __launch_bounds__(256)
void pre1_kernel(const float* __restrict__ x, const float* __restrict__ W1,
                 __half* __restrict__ msg1)
{
    const int grp = blockIdx.x & 3;
    const int wid = (blockIdx.x >> 2) * 4 + (threadIdx.x >> 6);
    const int nw = (gridDim.x >> 2) * 4;
    if (grp == 0)      pre1_work<0, 2>(x, W1, msg1, wid, nw);
    else if (grp == 1) pre1_work<2, 2>(x, W1, msg1, wid, nw);
    else if (grp == 2) pre1_work<4, 2>(x, W1, msg1, wid, nw);
    else               pre1_work<6, 1>(x, W1, msg1, wid, nw);
}

// ========== agg1: wave/node; 7 contiguous (dst,rel) segments; h = relu(root+bias+sum max) ==========
__global__ __launch_bounds__(256)
void agg1_kernel(const __half* __restrict__ msg1, const float* __restrict__ hrootp,
                 const float* __restrict__ bias1, const int* __restrict__ off2,
                 const int* __restrict__ packed1, float* __restrict__ h)
{
    const int lane = threadIdx.x & 63;
    const int lane2 = lane * 2;
    const char* m1 = (const char*)msg1;
    const int wid = blockIdx.x * 4 + (threadIdx.x >> 6);
    const int nw = gridDim.x * 4;
    const float bias = bias1[lane];

    for (int n = wid; n < N_NODES; n += nw) {
        const int4* ob = (const int4*)(off2 + (n << 3));
        const int4 oa = ob[0];   // v0..v3
        const int4 oc = ob[1];   // v4..v7
        float add = 0.f;

#define SEG1(st_, en_) { \
        const int st = st_, en = en_; \
        float m = NEGI; \
        int p = st; \
        for (; p + 1 < en; p += 2) { \
            int k0 = packed1[p], k1 = packed1[p + 1]; \
            float v0 = __half2float(*(const __half*)(m1 + (k0 + lane2))); \
            float v1 = __half2float(*(const __half*)(m1 + (k1 + lane2))); \
            m = fmaxf(m, fmaxf(v0, v1)); \
        } \
        if (p < en) { \
            int k0 = packed1[p]; \
            m = fmaxf(m, __half2float(*(const __half*)(m1 + (k0 + lane2)))); \
        } \
        if (en > st) add += m; }

        SEG1(oa.x, oa.y) SEG1(oa.y, oa.z) SEG1(oa.z, oa.w) SEG1(oa.w, oc.x)
        SEG1(oc.x, oc.y) SEG1(oc.y, oc.z) SEG1(oc.z, oc.w)
#undef SEG1

        const size_t hi = ((size_t)n << 6) + lane;
        float v = hrootp[hi] + hrootp[(size_t)N_NODES * HID_CH + hi] + bias + add;
        h[hi] = fmaxf(v, 0.f);
    }
}

// ========== pre2: msg2[n][16] = [h@W2[0..6] (2 each), h@root2+bias2 (2)] ==========
__global__ __launch_bounds__(256)
void pre2_kernel(const float* __restrict__ h, const float* __restrict__ comp2,
                 const float* __restrict__ basis2, const float* __restrict__ root2,
                 const float* __restrict__ bias2, float* __restrict__ msg2)
{
    const int lane = threadIdx.x & 63;
    const int sub = lane >> 4;   // node within quad
    const int o = lane & 15;     // output column 0..15

    float w[64];
    if (o < 14) {
        const int r = o >> 1, oc = o & 1;
        float c0 = comp2[r * NB + 0], c1 = comp2[r * NB + 1];
        float c2 = comp2[r * NB + 2], c3 = comp2[r * NB + 3];
#pragma unroll
        for (int i = 0; i < 64; ++i) {
            w[i] = c0 * basis2[(0 * HID_CH + i) * OUT_CH + oc]
                 + c1 * basis2[(1 * HID_CH + i) * OUT_CH + oc]
                 + c2 * basis2[(2 * HID_CH + i) * OUT_CH + oc]
                 + c3 * basis2[(3 * HID_CH + i) * OUT_CH + oc];
        }
    } else {
        const int oc = o - 14;
#pragma unroll
        for (int i = 0; i < 64; ++i) w[i] = root2[i * OUT_CH + oc];
    }
    const float badd = (o == 14) ? bias2[0] : ((o == 15) ? bias2[1] : 0.f);

    const int wid = blockIdx.x * 4 + (threadIdx.x >> 6);
    const int nw = gridDim.x * 4;
    const int NQUAD = N_NODES / 4;

    for (int nq = wid; nq < NQUAD; nq += nw) {
        const int n = nq * 4 + sub;
        const float4* hr = (const float4*)(h + ((size_t)n << 6));
        float acc = badd;
#pragma unroll
        for (int i4 = 0; i4 < 16; ++i4) {
            float4 hv = hr[i4];
            acc = fmaf(hv.x, w[i4 * 4 + 0], acc);
            acc = fmaf(hv.y, w[i4 * 4 + 1], acc);
            acc = fmaf(hv.z, w[i4 * 4 + 2], acc);
            acc = fmaf(hv.w, w[i4 * 4 + 3], acc);
        }
        msg2[(size_t)nq * 64 + lane] = acc;  // == msg2[n*16 + o], 256B/wave
    }
}

// ========== agg2: thread/node; 7 segments of float2 gathers ==========
__global__ __launch_bounds__(256)
void agg2_kernel(const float* __restrict__ msg2, const int* __restrict__ off2,
                 const int* __restrict__ packed2, float* __restrict__ out)
{
    const int n = blockIdx.x * blockDim.x + threadIdx.x;
    if (n >= N_NODES) return;
    const char* m2 = (const char*)msg2;
    const int4* ob = (const int4*)(off2 + (n << 3));
    const int4 oa = ob[0];
    const int4 oc = ob[1];
    float o0 = msg2[(size_t)n * 16 + 14];  // self + bias pre-folded
    float o1 = msg2[(size_t)n * 16 + 15];

#define SEG2(st_, en_) { \
    const int st = st_, en = en_; \
    float mx = NEGI, my = NEGI; \
    for (int p = st; p < en; ++p) { \
        const float2 f = *(const float2*)(m2 + packed2[p]); \
        mx = fmaxf(mx, f.x); \
        my = fmaxf(my, f.y); \
    } \
    if (en > st) { o0 += mx; o1 += my; } }

    SEG2(oa.x, oa.y) SEG2(oa.y, oa.z) SEG2(oa.z, oa.w) SEG2(oa.w, oc.x)
    SEG2(oc.x, oc.y) SEG2(oc.y, oc.z) SEG2(oc.z, oc.w)
#undef SEG2

    out[(size_t)n * OUT_CH + 0] = o0;
    out[(size_t)n * OUT_CH + 1] = o1;
}

extern "C" void kernel_launch(void* const* d_in, const int* in_sizes, int n_in,
                              void* d_out, int out_size, void* d_ws, size_t ws_size,
                              hipStream_t stream)
{
    const float* x      = (const float*)d_in[0];
    const int*   ei     = (const int*)d_in[1];
    const int*   et     = (const int*)d_in[2];
    const float* W1     = (const float*)d_in[3];
    const float* root1  = (const float*)d_in[4];
    const float* bias1  = (const float*)d_in[5];
    const float* comp2  = (const float*)d_in[6];
    const float* basis2 = (const float*)d_in[7];
    const float* root2  = (const float*)d_in[8];
    const float* bias2  = (const float*)d_in[9];
    float* out = (float*)d_out;

    // workspace carve-up (~191 MB; Path-A history shows ws >= 210 MB)
    char* ws = (char*)d_ws;
    size_t o = 0;
    auto carve = [&](size_t bytes) { char* p = ws + o; o += (bytes + 255) & ~(size_t)255; return p; };
    int*    deg2    = (int*)carve(sizeof(int) * NBINS);                                   //  3.2 MB
    int*    off2    = (int*)carve(sizeof(int) * (NBINS + 1));                             //  3.2 MB
    int*    cursor2 = (int*)carve(sizeof(int) * (NBINS + 1));                             //  3.2 MB
    int*    sums    = (int*)carve(sizeof(int) * 1024);
    int*    packed1 = (int*)carve(sizeof(int) * N_EDGESV);                                //  4.0 MB
    int*    packed2 = (int*)carve(sizeof(int) * N_EDGESV);                                //  4.0 MB
    __half* msg1    = (__half*)carve(sizeof(__half) * (size_t)N_NODES * N_REL * HID_CH);  // 89.6 MB
    float*  hrootp  = (float*)carve(sizeof(float) * 2 * (size_t)N_NODES * HID_CH);        // 51.2 MB
    float*  h       = (float*)carve(sizeof(float) * (size_t)N_NODES * HID_CH);            // 25.6 MB
    float*  msg2    = (float*)carve(sizeof(float) * (size_t)N_NODES * 16);                //  6.4 MB

    // ---- CSR build over (dst, rel) ----
    hipMemsetAsync(deg2, 0, sizeof(int) * NBINS, stream);
    hist_kernel<<<(N_EDGESV + 255) / 256, 256, 0, stream>>>(ei, et, deg2);
    scan1_kernel<<<NCHUNK2, 256, 0, stream>>>(deg2, off2, sums);
    scan2_kernel<<<1, 1024, 0, stream>>>(sums);
    scan3_kernel<<<(NBINS + 255) / 256, 256, 0, stream>>>(off2, sums, cursor2);
    scatter_kernel<<<(N_EDGESV + 255) / 256, 256, 0, stream>>>(ei, et, cursor2, packed1, packed2);

    // ---- dense precomputes ----
    rootmm_kernel<<<1024, 256, 0, stream>>>(x, root1, hrootp);
    pre1_kernel<<<2048, 256, 0, stream>>>(x, W1, msg1);

    // ---- layer 1 aggregation ----
    agg1_kernel<<<2048, 256, 0, stream>>>(msg1, hrootp, bias1, off2, packed1, h);

    // ---- layer 2 dense messages + aggregation ----
    pre2_kernel<<<1024, 256, 0, stream>>>(h, comp2, basis2, root2, bias2, msg2);
    agg2_kernel<<<(N_NODES + 255) / 256, 256, 0, stream>>>(msg2, off2, packed2, out);
}